// Round 14
// baseline (3226.804 us; speedup 1.0000x reference)
//
#include <hip/hip_runtime.h>
#include <math.h>

#define BB 64
#define SS 512
#define EE 256
#define HH 512

typedef unsigned long long ull;

// ---------------------------------------------------------------------------
// Projection GEMM (layer 0): out[m][n] = sum_k A[m][k]*Wih[n][k] + b1 + b2
// ---------------------------------------------------------------------------
template <int K>
__global__ __launch_bounds__(256) void k_proj(const float* __restrict__ Ain,
                                              const int* __restrict__ src,
                                              const float* __restrict__ emb,
                                              const float* __restrict__ Wih,
                                              const float* __restrict__ b1,
                                              const float* __restrict__ b2,
                                              float* __restrict__ out) {
    __shared__ __align__(16) float As[16][68];
    __shared__ __align__(16) float Bs[16][68];
    int tid = threadIdx.x;
    int m0 = blockIdx.x * 64;
    int n0 = blockIdx.y * 64;
    int tx = tid & 15, ty = tid >> 4;
    int lr = tid >> 2;
    int lc = (tid & 3) * 4;

    const float* arow;
    if (src) arow = emb + (size_t)src[m0 + lr] * EE;
    else     arow = Ain + (size_t)(m0 + lr) * K;
    const float* brow = Wih + (size_t)(n0 + lr) * K;

    float acc[4][4] = {};

    for (int k0 = 0; k0 < K; k0 += 16) {
        float4 av = *(const float4*)(arow + k0 + lc);
        float4 bv = *(const float4*)(brow + k0 + lc);
        __syncthreads();
        As[lc + 0][lr] = av.x; As[lc + 1][lr] = av.y;
        As[lc + 2][lr] = av.z; As[lc + 3][lr] = av.w;
        Bs[lc + 0][lr] = bv.x; Bs[lc + 1][lr] = bv.y;
        Bs[lc + 2][lr] = bv.z; Bs[lc + 3][lr] = bv.w;
        __syncthreads();
#pragma unroll
        for (int k = 0; k < 16; ++k) {
            float4 a = *(const float4*)&As[k][ty * 4];
            float4 b = *(const float4*)&Bs[k][tx * 4];
            acc[0][0] += a.x * b.x; acc[0][1] += a.x * b.y;
            acc[0][2] += a.x * b.z; acc[0][3] += a.x * b.w;
            acc[1][0] += a.y * b.x; acc[1][1] += a.y * b.y;
            acc[1][2] += a.y * b.z; acc[1][3] += a.y * b.w;
            acc[2][0] += a.z * b.x; acc[2][1] += a.z * b.y;
            acc[2][2] += a.z * b.z; acc[2][3] += a.z * b.w;
            acc[3][0] += a.w * b.x; acc[3][1] += a.w * b.y;
            acc[3][2] += a.w * b.z; acc[3][3] += a.w * b.w;
        }
    }

    int n = n0 + tx * 4;
    float bx_ = b1[n + 0] + b2[n + 0];
    float by_ = b1[n + 1] + b2[n + 1];
    float bz_ = b1[n + 2] + b2[n + 2];
    float bw_ = b1[n + 3] + b2[n + 3];
#pragma unroll
    for (int i = 0; i < 4; ++i) {
        int m = m0 + ty * 4 + i;
        float4 o;
        o.x = acc[i][0] + bx_; o.y = acc[i][1] + by_;
        o.z = acc[i][2] + bz_; o.w = acc[i][3] + bw_;
        *(float4*)(out + (size_t)m * HH + n) = o;
    }
}

// ---------------------------------------------------------------------------
// Fused 2-layer persistent recurrence, v8: v6's step engine + DEDICATED
// FINALIZE WAVE (producer/consumer specialization).
//
// r13 forensics: v6 is the best per-batch-step engine (2730 cyc) but loses
// ~1800cy/phase to the finalize-straggler chain (2 of 8 waves reduce+tanh+
// publish, then catch up poll+FMA before the next barrier, gating everyone).
// v7's shuffle alternative was worse (serialized ds-pipe chains). v8 keeps
// v6's validated engine (16 chunks x 16 slices(32 rows), 4 batches, 4 phases
// per tick, wave-internal LDS staging, red-LDS reduce) and adds wave 8
// (576 threads total) that ONLY finalizes: it processes the PREVIOUS phase's
// red buffer (redb[4] deep), loads pre, tanh x2, publishes, writes y. Its
// ~400cy of work < a compute phase -> it reaches barriers early; compute
// waves' phase is lean: poll -> stage -> FMA -> red-write -> barrier.
//
// Publish shifts one phase later -> consumer slack = 2 phases (~2200-3000cy)
// >= 3x RT (validated hit regime). 2-slot induction survives the shift:
// poll(bX,t) hit => all 16 blocks ran finalize(bX,t-1) (phase X+1, tick t-1)
// => all passed poll(bX,t-1) => the slot overwritten by publish(t+1) is dead.
// redb race-freedom: redb[p] written phase p (before its barrier), read by
// finalize in phase p+1, rewritten at phase p of the NEXT tick = 4 phases
// later. Stage buffers: parity 2 (written+read same phase, wave-internal).
//
// __launch_bounds__(576): 9 waves -> 3/SIMD worst case -> VGPR cap ~170;
// compute needs ~130 (96 weight floats VGPR-resident + addressing). 1 blk/CU.
// ---------------------------------------------------------------------------
__device__ __forceinline__ void phase8(
    int t, int bX,                      // compute job (this phase)
    int tF, int bF, bool fvalid,        // finalize job (previous phase)
    bool isC, int row, int ks, int kq, int kown, int grow,
    int half, int fr, int fgrow, float bias1,
    const float* __restrict__ pre,
    const float4* wA, const float4* wI, const float4* wH,
    ull* __restrict__ hp0, ull* __restrict__ hp1,
    float (*__restrict__ sb)[HH],              // stage, this parity: [2][512]
    float (*__restrict__ redW)[3][32],         // red write target: [16][3][32]
    const float (*__restrict__ redF)[3][32],   // red finalize source
    float* __restrict__ y, float& h0lF, float& h1lF) {
    if (isC) {
        // ---- compute role: poll -> stage -> FMA -> red-write ----
        const ull* s0p = hp0 + (size_t)(t & 1) * BB * HH + (size_t)bX * HH + kown;
        const ull* s1p = hp1 + (size_t)(t & 1) * BB * HH + (size_t)bX * HH + kown;
        ull q0, q1;
        const unsigned tt = (unsigned)t;
        for (;;) {
            q0 = __hip_atomic_load(s0p, __ATOMIC_RELAXED, __HIP_MEMORY_SCOPE_AGENT);
            q1 = __hip_atomic_load(s1p, __ATOMIC_RELAXED, __HIP_MEMORY_SCOPE_AGENT);
            unsigned d = (((unsigned)(q0 >> 32)) ^ tt) | (((unsigned)(q1 >> 32)) ^ tt);
            if (d == 0) break;
        }
        // wave-internal staging (consumers of [kq,kq+32) are in this wave)
        sb[0][kown] = __uint_as_float((unsigned)q0);
        sb[1][kown] = __uint_as_float((unsigned)q1);
        asm volatile("" ::: "memory");   // pin ds_write before ds_read

        const float4* x0 = (const float4*)&sb[0][kq];
        const float4* x1 = (const float4*)&sb[1][kq];
        float aa = 0.f, ai = 0.f, ah = 0.f;
#pragma unroll
        for (int i = 0; i < 8; ++i) {
            const float4 xv = x0[i];
            const float4 zv = x1[i];
            const float4 a4 = wA[i];
            const float4 i4 = wI[i];
            const float4 h4 = wH[i];
            aa = fmaf(a4.x, xv.x, aa); aa = fmaf(a4.y, xv.y, aa);
            aa = fmaf(a4.z, xv.z, aa); aa = fmaf(a4.w, xv.w, aa);
            ai = fmaf(i4.x, xv.x, ai); ai = fmaf(i4.y, xv.y, ai);
            ai = fmaf(i4.z, xv.z, ai); ai = fmaf(i4.w, xv.w, ai);
            ah = fmaf(h4.x, zv.x, ah); ah = fmaf(h4.y, zv.y, ah);
            ah = fmaf(h4.z, zv.z, ah); ah = fmaf(h4.w, zv.w, ah);
        }
        redW[ks][0][row] = aa; redW[ks][1][row] = ai; redW[ks][2][row] = ah;
    } else if (fvalid) {
        // ---- finalize role: reduce prev phase's red, tanh, publish, y ----
        if (half == 0) {
            float pv = 0.f;
            if (tF < SS) pv = pre[((size_t)bF * SS + tF) * HH + fgrow];
            float s0 = 0.f;
#pragma unroll
            for (int k2 = 0; k2 < 16; ++k2) s0 += redF[k2][0][fr];
            if (tF < SS) {
                float h0v = tanhf(pv + s0);
                h0lF = h0v;
                ull pk = ((ull)(unsigned)(tF + 1) << 32) | (ull)__float_as_uint(h0v);
                __hip_atomic_store(&hp0[(size_t)((tF + 1) & 1) * BB * HH + (size_t)bF * HH + fgrow],
                                   pk, __ATOMIC_RELAXED, __HIP_MEMORY_SCOPE_AGENT);
            }
        } else {
            float si = 0.f, sh = 0.f;
#pragma unroll
            for (int k2 = 0; k2 < 16; ++k2) { si += redF[k2][1][fr]; sh += redF[k2][2][fr]; }
            float h1v = tanhf(si + sh + bias1);
            h1lF = h1v;
            y[((size_t)bF * SS + (tF - 1)) * HH + fgrow] = h1v;
            if (tF < SS) {
                ull pk = ((ull)(unsigned)(tF + 1) << 32) | (ull)__float_as_uint(h1v);
                __hip_atomic_store(&hp1[(size_t)((tF + 1) & 1) * BB * HH + (size_t)bF * HH + fgrow],
                                   pk, __ATOMIC_RELAXED, __HIP_MEMORY_SCOPE_AGENT);
            }
        }
    }
    __syncthreads();   // one barrier per phase, uniform across all 9 waves
}

__global__ __launch_bounds__(576) void k_rec8(
    const float* __restrict__ pre,       // [B][S][H] layer0 input projection
    const float* __restrict__ Whh0,
    const float* __restrict__ Wih1,
    const float* __restrict__ Whh1,
    const float* __restrict__ b_ih1,
    const float* __restrict__ b_hh1,
    float* __restrict__ y,               // [B][S][H] layer1 output
    float* __restrict__ hlast,           // [2][B][H]
    ull* __restrict__ hp0,
    ull* __restrict__ hp1) {
    __shared__ __align__(16) float stg[2][2][HH];        // [parity][layer][512]
    __shared__ __align__(16) float redb[4][16][3][32];   // per-phase red

    const int tid = threadIdx.x;
    const int bid = blockIdx.x;
    const int g = bid & 15;              // row slice 0..15 (32 rows)
    const int c = bid >> 4;              // chunk 0..15 (4 batches)
    const int b0 = c * 4;

    const bool isC = (tid < 512);
    // compute-role indices (valid when isC)
    const int row = tid & 31;
    const int ks = tid >> 5;             // k-slice 0..15
    const int kq = (ks & 15) << 5;       // FMA k base (mask keeps tid>=512 sane)
    const int kown = isC ? tid : 0;      // polled k
    const int grow = g * 32 + row;
    // finalize-role indices (valid when !isC)
    const int fl = tid - 512;            // 0..63
    const int fr = fl & 31;              // row
    const int half = fl >> 5;            // 0: h0 outputs, 1: h1 outputs
    const int fgrow = g * 32 + (fr & 31);

    // compute-wave weights: row grow, k in [kq,kq+32), 3 units = 96 floats
    float4 wA[8], wI[8], wH[8];
    if (isC) {
        const float* pA = Whh0 + (size_t)grow * HH + kq;
        const float* pI = Wih1 + (size_t)grow * HH + kq;
        const float* pH = Whh1 + (size_t)grow * HH + kq;
#pragma unroll
        for (int i = 0; i < 8; ++i) {
            wA[i] = *(const float4*)(pA + i * 4);
            wI[i] = *(const float4*)(pI + i * 4);
            wH[i] = *(const float4*)(pH + i * 4);
        }
    }

    // finalize-wave state
    float bias1 = 0.f;
    float h0l0 = 0.f, h0l1 = 0.f, h0l2 = 0.f, h0l3 = 0.f;
    float h1l0 = 0.f, h1l1 = 0.f, h1l2 = 0.f, h1l3 = 0.f;
    if (!isC) {
        if (half == 1) bias1 = b_ih1[fgrow] + b_hh1[fgrow];
        // prologue: per batch, h0(0)=tanh(pre[0]) tag 1; h1(-1)=0 tag 1
#pragma unroll
        for (int X = 0; X < 4; ++X) {
            const int bX = b0 + X;
            if (half == 0) {
                float v = tanhf(pre[(size_t)bX * SS * HH + fgrow]);
                if (X == 0) h0l0 = v; else if (X == 1) h0l1 = v;
                else if (X == 2) h0l2 = v; else h0l3 = v;
                ull pk = (1ULL << 32) | (ull)__float_as_uint(v);
                __hip_atomic_store(&hp0[(size_t)1 * BB * HH + (size_t)bX * HH + fgrow],
                                   pk, __ATOMIC_RELAXED, __HIP_MEMORY_SCOPE_AGENT);
            } else {
                __hip_atomic_store(&hp1[(size_t)1 * BB * HH + (size_t)bX * HH + fgrow],
                                   (1ULL << 32), __ATOMIC_RELAXED, __HIP_MEMORY_SCOPE_AGENT);
            }
        }
    }

    for (int t = 1; t <= SS; ++t) {
        // phase p computes (b0+p, t); finalize handles previous phase's red
        phase8(t, b0 + 0, t - 1, b0 + 3, (t > 1), isC, row, ks, kq, kown, grow,
               half, fr, fgrow, bias1, pre, wA, wI, wH, hp0, hp1,
               stg[0], redb[0], redb[3], y, h0l3, h1l3);
        phase8(t, b0 + 1, t, b0 + 0, true, isC, row, ks, kq, kown, grow,
               half, fr, fgrow, bias1, pre, wA, wI, wH, hp0, hp1,
               stg[1], redb[1], redb[0], y, h0l0, h1l0);
        phase8(t, b0 + 2, t, b0 + 1, true, isC, row, ks, kq, kown, grow,
               half, fr, fgrow, bias1, pre, wA, wI, wH, hp0, hp1,
               stg[0], redb[2], redb[1], y, h0l1, h1l1);
        phase8(t, b0 + 3, t, b0 + 2, true, isC, row, ks, kq, kown, grow,
               half, fr, fgrow, bias1, pre, wA, wI, wH, hp0, hp1,
               stg[1], redb[3], redb[2], y, h0l2, h1l2);
    }

    // epilogue: finalize the last pending red (b0+3, tick SS); tF==SS so
    // only the h1 side produces output (y[SS-1], h1last). No publishes.
    if (!isC) {
        if (half == 1) {
            float si = 0.f, sh = 0.f;
#pragma unroll
            for (int k2 = 0; k2 < 16; ++k2) { si += redb[3][k2][1][fr]; sh += redb[3][k2][2][fr]; }
            float h1v = tanhf(si + sh + bias1);
            h1l3 = h1v;
            y[((size_t)(b0 + 3) * SS + (SS - 1)) * HH + fgrow] = h1v;
        }
        // hlast: layer0 from half==0 lanes, layer1 from half==1 lanes
        if (half == 0) {
            hlast[(size_t)(b0 + 0) * HH + fgrow] = h0l0;
            hlast[(size_t)(b0 + 1) * HH + fgrow] = h0l1;
            hlast[(size_t)(b0 + 2) * HH + fgrow] = h0l2;
            hlast[(size_t)(b0 + 3) * HH + fgrow] = h0l3;
        } else {
            hlast[(size_t)BB * HH + (size_t)(b0 + 0) * HH + fgrow] = h1l0;
            hlast[(size_t)BB * HH + (size_t)(b0 + 1) * HH + fgrow] = h1l1;
            hlast[(size_t)BB * HH + (size_t)(b0 + 2) * HH + fgrow] = h1l2;
            hlast[(size_t)BB * HH + (size_t)(b0 + 3) * HH + fgrow] = h1l3;
        }
    }
}

// ---------------------------------------------------------------------------
extern "C" void kernel_launch(void* const* d_in, const int* in_sizes, int n_in,
                              void* d_out, int out_size, void* d_ws, size_t ws_size,
                              hipStream_t stream) {
    const int*   src   = (const int*)d_in[0];
    const float* emb   = (const float*)d_in[1];
    const float* W_ih0 = (const float*)d_in[2];
    const float* W_hh0 = (const float*)d_in[3];
    const float* b_ih0 = (const float*)d_in[4];
    const float* b_hh0 = (const float*)d_in[5];
    const float* W_ih1 = (const float*)d_in[6];
    const float* W_hh1 = (const float*)d_in[7];
    const float* b_ih1 = (const float*)d_in[8];
    const float* b_hh1 = (const float*)d_in[9];

    float* out   = (float*)d_out;
    float* y_out = out;                               // [B][S][H] (layer1 y)
    float* hlast = out + (size_t)BB * SS * HH;        // [2][B][H]

    float* ws  = (float*)d_ws;
    float* pre = ws;                                  // [B][S][H] layer0 proj
    ull* hp0 = (ull*)(ws + (size_t)BB * SS * HH);
    ull* hp1 = hp0 + (size_t)2 * BB * HH;

    // Layer-0 input projection (embedding gather fused in)
    k_proj<EE><<<dim3(512, 8), 256, 0, stream>>>(nullptr, src, emb, W_ih0,
                                                 b_ih0, b_hh0, pre);
    // Fused 2-layer recurrence: v6 engine + dedicated finalize wave
    k_rec8<<<256, 576, 0, stream>>>(pre, W_hh0, W_ih1, W_hh1, b_ih1, b_hh1,
                                    y_out, hlast, hp0, hp1);
}

// Round 16
// 1598.195 us; speedup vs baseline: 2.0190x; 2.0190x over previous
//
#include <hip/hip_runtime.h>
#include <math.h>

#define BB 64
#define SS 512
#define EE 256
#define HH 512

typedef unsigned long long ull;

// ---------------------------------------------------------------------------
// Projection GEMM (layer 0): out[m][n] = sum_k A[m][k]*Wih[n][k] + b1 + b2
// ---------------------------------------------------------------------------
template <int K>
__global__ __launch_bounds__(256) void k_proj(const float* __restrict__ Ain,
                                              const int* __restrict__ src,
                                              const float* __restrict__ emb,
                                              const float* __restrict__ Wih,
                                              const float* __restrict__ b1,
                                              const float* __restrict__ b2,
                                              float* __restrict__ out) {
    __shared__ __align__(16) float As[16][68];
    __shared__ __align__(16) float Bs[16][68];
    int tid = threadIdx.x;
    int m0 = blockIdx.x * 64;
    int n0 = blockIdx.y * 64;
    int tx = tid & 15, ty = tid >> 4;
    int lr = tid >> 2;
    int lc = (tid & 3) * 4;

    const float* arow;
    if (src) arow = emb + (size_t)src[m0 + lr] * EE;
    else     arow = Ain + (size_t)(m0 + lr) * K;
    const float* brow = Wih + (size_t)(n0 + lr) * K;

    float acc[4][4] = {};

    for (int k0 = 0; k0 < K; k0 += 16) {
        float4 av = *(const float4*)(arow + k0 + lc);
        float4 bv = *(const float4*)(brow + k0 + lc);
        __syncthreads();
        As[lc + 0][lr] = av.x; As[lc + 1][lr] = av.y;
        As[lc + 2][lr] = av.z; As[lc + 3][lr] = av.w;
        Bs[lc + 0][lr] = bv.x; Bs[lc + 1][lr] = bv.y;
        Bs[lc + 2][lr] = bv.z; Bs[lc + 3][lr] = bv.w;
        __syncthreads();
#pragma unroll
        for (int k = 0; k < 16; ++k) {
            float4 a = *(const float4*)&As[k][ty * 4];
            float4 b = *(const float4*)&Bs[k][tx * 4];
            acc[0][0] += a.x * b.x; acc[0][1] += a.x * b.y;
            acc[0][2] += a.x * b.z; acc[0][3] += a.x * b.w;
            acc[1][0] += a.y * b.x; acc[1][1] += a.y * b.y;
            acc[1][2] += a.y * b.z; acc[1][3] += a.y * b.w;
            acc[2][0] += a.z * b.x; acc[2][1] += a.z * b.y;
            acc[2][2] += a.z * b.z; acc[2][3] += a.z * b.w;
            acc[3][0] += a.w * b.x; acc[3][1] += a.w * b.y;
            acc[3][2] += a.w * b.z; acc[3][3] += a.w * b.w;
        }
    }

    int n = n0 + tx * 4;
    float bx_ = b1[n + 0] + b2[n + 0];
    float by_ = b1[n + 1] + b2[n + 1];
    float bz_ = b1[n + 2] + b2[n + 2];
    float bw_ = b1[n + 3] + b2[n + 3];
#pragma unroll
    for (int i = 0; i < 4; ++i) {
        int m = m0 + ty * 4 + i;
        float4 o;
        o.x = acc[i][0] + bx_; o.y = acc[i][1] + by_;
        o.z = acc[i][2] + bz_; o.w = acc[i][3] + bw_;
        *(float4*)(out + (size_t)m * HH + n) = o;
    }
}

// ---------------------------------------------------------------------------
// Fused 2-layer persistent recurrence, v9 = r7 (the measured best, 1860us)
// with ONE surgical change: the readlane broadcast in the inner loop is
// replaced by wave-internal LDS staging + ds_read_b128 broadcast reads.
//
// r7 recap (all preserved): 256 blocks = 32 chunks(2 batches) x 8 slices
// (64 rows); 512 thr = 8 waves; lane r of wave w polls kown = w*64+r in
// both hp0/hp1; batch-phased A/B ticks; redA/redB cross-wave reduce with one
// barrier per phase; finalize wave 0 -> h0(t), wave 1 -> h1(t-1); 192 weight
// floats/thread (VGPR+AGPR unified, launch_bounds(512,2)).
//
// The change: r7 burned 128 v_readlane per phase per thread (2 per 3 fmas).
// Now each wave writes its polled 64-k segment to h-LDS (2 ds_write_b32,
// 2 lanes/bank = free) and the FMA loop reads it back as 2x16 ds_read_b128
// (all lanes same address = LDS broadcast, conflict-free). Write->read is
// same-wave program order -> in-order DS pipe -> NO barrier (pattern
// HW-validated in r10: passed absmax). Phase A and B reuse the same h-LDS
// addresses: the overwrite is also same-wave-ordered after the reads.
// Inner loop: 14 instr per 4 k (2 b128 + 12 fma) vs r7's 20 -> ~35% less
// issue in the dominant loop.
//
// Exchange protocol byte-identical to r7 (tag-in-data {f32,u32 tag} 8B
// relaxed agent atomics, 2-slot per-layer buffers, tick-t polls tag t in
// slot t&1, publish tag t+1 into slot (t+1)&1; 2-slot induction per batch
// chain; 0xAA poison never matches tags 1..512).
// ---------------------------------------------------------------------------
__device__ __forceinline__ void rec_phase9(
    int t, int bX, int grow, int r, int w, int kown, int wbase,
    const float* __restrict__ pre,
    const float4* wA, const float4* wI, const float4* wH, float bias1,
    ull* __restrict__ hp0, ull* __restrict__ hp1,
    float* __restrict__ h0s, float* __restrict__ h1s,
    float (*red)[3][64],
    float* __restrict__ y, float& h0last, float& h1last) {
    // prefetch this batch's pre value (finalize waves only; hides under poll)
    float pv = 0.f;
    if (w == 0 && t < SS) pv = pre[((size_t)bX * SS + t) * HH + grow];

    // poll own k in both layer buffers (tags must equal t)
    const ull* s0p = hp0 + (size_t)(t & 1) * BB * HH + (size_t)bX * HH + kown;
    const ull* s1p = hp1 + (size_t)(t & 1) * BB * HH + (size_t)bX * HH + kown;
    ull q0, q1;
    const unsigned tt = (unsigned)t;
    for (;;) {
        q0 = __hip_atomic_load(s0p, __ATOMIC_RELAXED, __HIP_MEMORY_SCOPE_AGENT);
        q1 = __hip_atomic_load(s1p, __ATOMIC_RELAXED, __HIP_MEMORY_SCOPE_AGENT);
        unsigned d = (((unsigned)(q0 >> 32)) ^ tt) | (((unsigned)(q1 >> 32)) ^ tt);
        if (d == 0) break;
    }
    // wave-internal staging: this wave's 64-k segment, consumed only by this
    // wave's own lanes -> no barrier (in-order DS pipe; compiler fence).
    h0s[kown] = __uint_as_float((unsigned)q0);
    h1s[kown] = __uint_as_float((unsigned)q1);
    asm volatile("" ::: "memory");

    // 3 matvec units over [wbase, wbase+64): broadcast b128 reads + fma
    const float4* x0 = (const float4*)&h0s[wbase];
    const float4* x1 = (const float4*)&h1s[wbase];
    float aa = 0.f, ai = 0.f, ah = 0.f;
#pragma unroll
    for (int i = 0; i < 16; ++i) {
        const float4 xv = x0[i];
        const float4 zv = x1[i];
        const float4 a4 = wA[i];
        const float4 i4 = wI[i];
        const float4 h4 = wH[i];
        aa = fmaf(a4.x, xv.x, aa); aa = fmaf(a4.y, xv.y, aa);
        aa = fmaf(a4.z, xv.z, aa); aa = fmaf(a4.w, xv.w, aa);
        ai = fmaf(i4.x, xv.x, ai); ai = fmaf(i4.y, xv.y, ai);
        ai = fmaf(i4.z, xv.z, ai); ai = fmaf(i4.w, xv.w, ai);
        ah = fmaf(h4.x, zv.x, ah); ah = fmaf(h4.y, zv.y, ah);
        ah = fmaf(h4.z, zv.z, ah); ah = fmaf(h4.w, zv.w, ah);
    }
    red[w][0][r] = aa; red[w][1][r] = ai; red[w][2][r] = ah;
    __syncthreads();

    // finalize: wave 0 -> h0_X(t); wave 1 -> h1_X(t-1); others run ahead
    if (w == 0) {
        if (t < SS) {
            float s0 = red[0][0][r] + red[1][0][r] + red[2][0][r] + red[3][0][r] +
                       red[4][0][r] + red[5][0][r] + red[6][0][r] + red[7][0][r];
            float h0v = tanhf(pv + s0);
            h0last = h0v;
            ull pk = ((ull)(unsigned)(t + 1) << 32) | (ull)__float_as_uint(h0v);
            __hip_atomic_store(&hp0[(size_t)((t + 1) & 1) * BB * HH + (size_t)bX * HH + grow],
                               pk, __ATOMIC_RELAXED, __HIP_MEMORY_SCOPE_AGENT);
        }
    } else if (w == 1) {
        float si = red[0][1][r] + red[1][1][r] + red[2][1][r] + red[3][1][r] +
                   red[4][1][r] + red[5][1][r] + red[6][1][r] + red[7][1][r];
        float sh = red[0][2][r] + red[1][2][r] + red[2][2][r] + red[3][2][r] +
                   red[4][2][r] + red[5][2][r] + red[6][2][r] + red[7][2][r];
        float h1v = tanhf(si + sh + bias1);
        h1last = h1v;
        y[((size_t)bX * SS + (t - 1)) * HH + grow] = h1v;
        if (t < SS) {
            ull pk = ((ull)(unsigned)(t + 1) << 32) | (ull)__float_as_uint(h1v);
            __hip_atomic_store(&hp1[(size_t)((t + 1) & 1) * BB * HH + (size_t)bX * HH + grow],
                               pk, __ATOMIC_RELAXED, __HIP_MEMORY_SCOPE_AGENT);
        }
    }
}

__global__ __launch_bounds__(512, 2) void k_rec9(
    const float* __restrict__ pre,       // [B][S][H] layer0 input projection
    const float* __restrict__ Whh0,
    const float* __restrict__ Wih1,
    const float* __restrict__ Whh1,
    const float* __restrict__ b_ih1,
    const float* __restrict__ b_hh1,
    float* __restrict__ y,               // [B][S][H] layer1 output
    float* __restrict__ hlast,           // [2][B][H]
    ull* __restrict__ hp0,
    ull* __restrict__ hp1) {
    __shared__ __align__(16) float h0s[HH], h1s[HH];
    __shared__ __align__(16) float redA[8][3][64], redB[8][3][64];

    const int tid = threadIdx.x;
    const int r = tid & 63;
    const int w = tid >> 6;              // k-eighth 0..7
    const int bid = blockIdx.x;
    const int g = bid & 7;               // row slice 0..7 (64 rows)
    const int c = bid >> 3;              // batch chunk 0..31
    const int grow = g * 64 + r;
    const int kown = w * 64 + r;         // polled k (both layers)
    const int wbase = w * 64;            // this wave's staged k segment
    const int bA = c * 2, bB = c * 2 + 1;

    // three 64x512 weight slices -> register file (192 floats, one-time)
    float4 wA[16], wI[16], wH[16];
    {
        const float* pA = Whh0 + (size_t)grow * HH + wbase;
        const float* pI = Wih1 + (size_t)grow * HH + wbase;
        const float* pH = Whh1 + (size_t)grow * HH + wbase;
#pragma unroll
        for (int i = 0; i < 16; ++i) {
            wA[i] = *(const float4*)(pA + i * 4);
            wI[i] = *(const float4*)(pI + i * 4);
            wH[i] = *(const float4*)(pH + i * 4);
        }
    }

    // ---- prologue: per batch, h0(0)=tanh(pre[0]) tag 1; h1(-1)=0 tag 1 ----
    float h0lA = 0.f, h0lB = 0.f, h1lA = 0.f, h1lB = 0.f, bias1 = 0.f;
    if (w == 0) {
        float pA0 = pre[(size_t)bA * SS * HH + grow];
        h0lA = tanhf(pA0);
        ull pk = (1ULL << 32) | (ull)__float_as_uint(h0lA);
        __hip_atomic_store(&hp0[(size_t)1 * BB * HH + (size_t)bA * HH + grow], pk,
                           __ATOMIC_RELAXED, __HIP_MEMORY_SCOPE_AGENT);
        float pB0 = pre[(size_t)bB * SS * HH + grow];
        h0lB = tanhf(pB0);
        pk = (1ULL << 32) | (ull)__float_as_uint(h0lB);
        __hip_atomic_store(&hp0[(size_t)1 * BB * HH + (size_t)bB * HH + grow], pk,
                           __ATOMIC_RELAXED, __HIP_MEMORY_SCOPE_AGENT);
    } else if (w == 1) {
        bias1 = b_ih1[grow] + b_hh1[grow];
        ull pk = (1ULL << 32);           // h1(-1) = 0
        __hip_atomic_store(&hp1[(size_t)1 * BB * HH + (size_t)bA * HH + grow], pk,
                           __ATOMIC_RELAXED, __HIP_MEMORY_SCOPE_AGENT);
        __hip_atomic_store(&hp1[(size_t)1 * BB * HH + (size_t)bB * HH + grow], pk,
                           __ATOMIC_RELAXED, __HIP_MEMORY_SCOPE_AGENT);
    }

    for (int t = 1; t <= SS; ++t) {
        // phase A (batch 2c): tag-t data published one B-phase ago
        rec_phase9(t, bA, grow, r, w, kown, wbase, pre, wA, wI, wH, bias1,
                   hp0, hp1, h0s, h1s, redA, y, h0lA, h1lA);
        // phase B (batch 2c+1): tag-t data published one A-phase ago
        rec_phase9(t, bB, grow, r, w, kown, wbase, pre, wA, wI, wH, bias1,
                   hp0, hp1, h0s, h1s, redB, y, h0lB, h1lB);
    }

    if (w == 0) {
        hlast[(size_t)bA * HH + grow] = h0lA;                        // layer0
        hlast[(size_t)bB * HH + grow] = h0lB;
    } else if (w == 1) {
        hlast[(size_t)BB * HH + (size_t)bA * HH + grow] = h1lA;      // layer1
        hlast[(size_t)BB * HH + (size_t)bB * HH + grow] = h1lB;
    }
}

// ---------------------------------------------------------------------------
extern "C" void kernel_launch(void* const* d_in, const int* in_sizes, int n_in,
                              void* d_out, int out_size, void* d_ws, size_t ws_size,
                              hipStream_t stream) {
    const int*   src   = (const int*)d_in[0];
    const float* emb   = (const float*)d_in[1];
    const float* W_ih0 = (const float*)d_in[2];
    const float* W_hh0 = (const float*)d_in[3];
    const float* b_ih0 = (const float*)d_in[4];
    const float* b_hh0 = (const float*)d_in[5];
    const float* W_ih1 = (const float*)d_in[6];
    const float* W_hh1 = (const float*)d_in[7];
    const float* b_ih1 = (const float*)d_in[8];
    const float* b_hh1 = (const float*)d_in[9];

    float* out   = (float*)d_out;
    float* y_out = out;                               // [B][S][H] (layer1 y)
    float* hlast = out + (size_t)BB * SS * HH;        // [2][B][H]

    float* ws  = (float*)d_ws;
    float* pre = ws;                                  // [B][S][H] layer0 proj
    ull* hp0 = (ull*)(ws + (size_t)BB * SS * HH);
    ull* hp1 = hp0 + (size_t)2 * BB * HH;

    // Layer-0 input projection (embedding gather fused in)
    k_proj<EE><<<dim3(512, 8), 256, 0, stream>>>(nullptr, src, emb, W_ih0,
                                                 b_ih0, b_hh0, pre);
    // Fused 2-layer recurrence: r7 structure + LDS-broadcast inner loop
    k_rec9<<<256, 512, 0, stream>>>(pre, W_hh0, W_ih1, W_hh1, b_ih1, b_hh1,
                                    y_out, hlast, hp0, hp1);
}